// Round 4
// baseline (194.931 us; speedup 1.0000x reference)
//
#include <hip/hip_runtime.h>
#include <hip/hip_bf16.h>
#include <stdint.h>

// B=8, S=2048, D=256. out[b,d] = (1/S) sum_k w_k v[b,k,d],
// w_k = sum_q P_qk / l_q,  P_qk = exp(s_qk) (0 for masked k), l_q = sum_k P_qk.
// k_proj3: fused fp32->bf16 + QKV projection GEMM (LDS-tiled).
// k_attn:  K-resident barrier-free QK^T -> P tiles (fp16) + l_q atomics.
// k_wred3: column-reduce P tiles over q -> w_k.
// k_out:   out = (1/S) * wsum . V.

typedef short short8 __attribute__((ext_vector_type(8)));
typedef float floatx4 __attribute__((ext_vector_type(4)));

#define MFMA16(a, b, c) __builtin_amdgcn_mfma_f32_16x16x32_bf16((a), (b), (c), 0, 0, 0)

static __device__ __forceinline__ unsigned short f2bf(float f) {
    union { float f; unsigned u; } v; v.f = f;
    unsigned r = v.u + 0x7fffu + ((v.u >> 16) & 1u);
    return (unsigned short)(r >> 16);
}
static __device__ __forceinline__ float bf2f(unsigned short h) {
    union { unsigned u; float f; } v; v.u = ((unsigned)h) << 16;
    return v.f;
}
static __device__ __forceinline__ short8 cvt8(float4 a, float4 b) {
    short8 o;
    o[0] = f2bf(a.x); o[1] = f2bf(a.y); o[2] = f2bf(a.z); o[3] = f2bf(a.w);
    o[4] = f2bf(b.x); o[5] = f2bf(b.y); o[6] = f2bf(b.z); o[7] = f2bf(b.w);
    return o;
}

// ---------------- k_proj3: fp32 inputs, 128x128 LDS-tiled GEMM --------------
// grid (128, 2, 3); block 256 = 4 waves (2x2), wave computes 64x64.
// LDS: 16B chunks, slot p -> (row=p>>3, col8=(p&7)^(row&7)): conflict-free
// staging writes, 2-way (free) fragment reads.
__global__ __launch_bounds__(256) void k_proj3(
    const float* __restrict__ nodes,   // [16384][256] fp32
    const float* __restrict__ Wq, const float* __restrict__ Wk,
    const float* __restrict__ Wv,
    const float* __restrict__ bq, const float* __restrict__ bk,
    const float* __restrict__ bv,
    unsigned short* __restrict__ qb, unsigned short* __restrict__ kb,
    unsigned short* __restrict__ vb)
{
    __shared__ unsigned short As[128 * 64];
    __shared__ unsigned short Bs[128 * 64];
    int tid = threadIdx.x, lane = tid & 63, wave = tid >> 6;
    int wm = wave & 1, wn = wave >> 1;
    int l15 = lane & 15, quad = lane >> 4;
    int mBase = blockIdx.x * 128;
    int nBase = blockIdx.y * 128;
    int z = blockIdx.z;
    const float* W = (z == 0) ? Wq : (z == 1 ? Wk : Wv);

    floatx4 acc[4][4] = {};

    int srow[4], scol[4];
#pragma unroll
    for (int i = 0; i < 4; ++i) {
        int p = i * 256 + tid;
        srow[i] = p >> 3;
        scol[i] = (p & 7) ^ (srow[i] & 7);
    }

    for (int kc = 0; kc < 256; kc += 64) {
#pragma unroll
        for (int i = 0; i < 4; ++i) {
            int p = i * 256 + tid;
            const float* ap = nodes + (mBase + srow[i]) * 256 + kc + scol[i] * 8;
            const float* bp = W + (nBase + srow[i]) * 256 + kc + scol[i] * 8;
            *(short8*)(&As[p * 8]) = cvt8(*(const float4*)ap, *(const float4*)(ap + 4));
            *(short8*)(&Bs[p * 8]) = cvt8(*(const float4*)bp, *(const float4*)(bp + 4));
        }
        __syncthreads();
#pragma unroll
        for (int ks = 0; ks < 2; ++ks) {
            int c8 = ks * 4 + quad;
            short8 af[4], bfr[4];
#pragma unroll
            for (int i = 0; i < 4; ++i) {
                int row = wm * 64 + i * 16 + l15;
                af[i] = *(const short8*)(&As[(row * 8 + (c8 ^ (row & 7))) * 8]);
            }
#pragma unroll
            for (int i = 0; i < 4; ++i) {
                int row = wn * 64 + i * 16 + l15;
                bfr[i] = *(const short8*)(&Bs[(row * 8 + (c8 ^ (row & 7))) * 8]);
            }
#pragma unroll
            for (int mi = 0; mi < 4; ++mi)
#pragma unroll
                for (int ni = 0; ni < 4; ++ni)
                    acc[mi][ni] = MFMA16(af[mi], bfr[ni], acc[mi][ni]);
        }
        __syncthreads();
    }

    const float* bias = (z == 0) ? bq : (z == 1 ? bk : bv);
    unsigned short* out = (z == 0) ? qb : (z == 1 ? kb : vb);
    float scale = (z == 0) ? 0.0625f : 1.0f;   // fold 1/sqrt(256) into q
#pragma unroll
    for (int mi = 0; mi < 4; ++mi)
#pragma unroll
        for (int ni = 0; ni < 4; ++ni) {
            int col = nBase + wn * 64 + ni * 16 + l15;
            float bval = bias[col];
#pragma unroll
            for (int r = 0; r < 4; ++r) {
                int row = mBase + wm * 64 + mi * 16 + quad * 4 + r;
                out[row * 256 + col] = f2bf((acc[mi][ni][r] + bval) * scale);
            }
        }
}

// ---------------- k_attn: K-resident barrier-free QK^T + exp + P + l_q ------
// grid (16 kblk, 8 qsplit, 8 b); block 256 = 4 waves.
// Wave owns 32 keys: kf (2 nt-tiles x 8 ks) resident in regs; streams
// 32-query chunks (direct global A-frag loads). No LDS, no __syncthreads.
// P layout: [b][ktile(128)][qcg(64)][lane(64)][8 fp16]; per (ktile,qcg) 1KB.
__global__ __launch_bounds__(256, 2) void k_attn(
    const unsigned short* __restrict__ qb, const unsigned short* __restrict__ kb,
    const int* __restrict__ mask, float* __restrict__ lsum_g,
    unsigned short* __restrict__ pbuf)
{
    int tid = threadIdx.x, lane = tid & 63, wave = tid >> 6;
    int l15 = lane & 15, quad = lane >> 4;
    int b = blockIdx.z;
    int kbase = blockIdx.x * 128 + wave * 32;
    int qs = blockIdx.y * 256;

    // resident K fragments + per-lane mask bias
    short8 kf[2][8];
    float mb[2];
#pragma unroll
    for (int nt = 0; nt < 2; ++nt) {
        int krow = b * 2048 + kbase + nt * 16 + l15;
#pragma unroll
        for (int ks = 0; ks < 8; ++ks)
            kf[nt][ks] = *(const short8*)(kb + krow * 256 + ks * 32 + quad * 8);
        mb[nt] = mask[b * 2048 + kbase + nt * 16 + l15] ? 0.0f : -1e30f;
    }

    for (int qc = 0; qc < 8; ++qc) {
        int qBase = qs + qc * 32;
        short8 af[2][8];
#pragma unroll
        for (int mi = 0; mi < 2; ++mi) {
            int qrow = b * 2048 + qBase + mi * 16 + l15;
#pragma unroll
            for (int ks = 0; ks < 8; ++ks)
                af[mi][ks] = *(const short8*)(qb + qrow * 256 + ks * 32 + quad * 8);
        }
        floatx4 acc[2][2] = {};
#pragma unroll
        for (int ks = 0; ks < 8; ++ks) {
            acc[0][0] = MFMA16(af[0][ks], kf[0][ks], acc[0][0]);
            acc[0][1] = MFMA16(af[0][ks], kf[1][ks], acc[0][1]);
            acc[1][0] = MFMA16(af[1][ks], kf[0][ks], acc[1][0]);
            acc[1][1] = MFMA16(af[1][ks], kf[1][ks], acc[1][1]);
        }
        // exp, P pack/store, l partials
        float e[2][2][4];
#pragma unroll
        for (int mi = 0; mi < 2; ++mi)
#pragma unroll
            for (int nt = 0; nt < 2; ++nt)
#pragma unroll
                for (int r = 0; r < 4; ++r)
                    e[mi][nt][r] = __expf(acc[mi][nt][r] + mb[nt]);

        int qcg = blockIdx.y * 8 + qc;
#pragma unroll
        for (int nt = 0; nt < 2; ++nt) {
            short8 hh;
#pragma unroll
            for (int mi = 0; mi < 2; ++mi)
#pragma unroll
                for (int r = 0; r < 4; ++r) {
                    union { _Float16 h; short s; } u;
                    u.h = (_Float16)e[mi][nt][r];
                    hh[mi * 4 + r] = u.s;
                }
            int ktile = blockIdx.x * 8 + wave * 2 + nt;
            size_t off = ((((size_t)b * 128 + ktile) * 64 + qcg) * 64 + lane) * 8;
            *(short8*)(pbuf + off) = hh;
        }
#pragma unroll
        for (int mi = 0; mi < 2; ++mi)
#pragma unroll
            for (int r = 0; r < 4; ++r) {
                float v = e[mi][0][r] + e[mi][1][r];
                v += __shfl_xor(v, 1); v += __shfl_xor(v, 2);
                v += __shfl_xor(v, 4); v += __shfl_xor(v, 8);
                if (l15 == 0)
                    atomicAdd(&lsum_g[b * 2048 + qBase + mi * 16 + quad * 4 + r], v);
            }
    }
}

// ---------------- k_wred3: w_k = sum_q P[q][k] / l_q --------------------------
// grid (2 qhalf, 16 kblk, 8 b); block 512 = 8 waves, wave -> one ktile.
// linv pre-permuted in LDS so each lane's 8 scales are 2 broadcast b128 reads.
__global__ __launch_bounds__(512) void k_wred3(
    const unsigned short* __restrict__ pbuf, const float* __restrict__ lsum_g,
    float* __restrict__ wsum_g)
{
    __shared__ float linv_p[2048];   // [qcg(64)][quad(4)][mi*4+r(8)]
    int tid = threadIdx.x, lane = tid & 63, wave = tid >> 6;
    int l15 = lane & 15, quad = lane >> 4;
    int b = blockIdx.z;
    int ktile = blockIdx.y * 8 + wave;

#pragma unroll
    for (int i = 0; i < 4; ++i) {
        int idx = i * 512 + tid;
        int qcg = idx >> 5, qd = (idx >> 3) & 3, j = idx & 7;
        int q = qcg * 32 + (j >> 2) * 16 + qd * 4 + (j & 3);
        linv_p[idx] = 1.0f / lsum_g[b * 2048 + q];
    }
    __syncthreads();

    int qcg0 = blockIdx.x * 32;
    float acc = 0.f;
#pragma unroll 4
    for (int qcg = qcg0; qcg < qcg0 + 32; ++qcg) {
        size_t off = ((((size_t)b * 128 + ktile) * 64 + qcg) * 64 + lane) * 8;
        short8 pv = *(const short8*)(pbuf + off);
        const float* lv = &linv_p[(qcg * 4 + quad) * 8];
        floatx4 l0 = *(const floatx4*)lv;
        floatx4 l1 = *(const floatx4*)(lv + 4);
#pragma unroll
        for (int j = 0; j < 4; ++j) {
            union { short s; _Float16 h; } u0, u1;
            u0.s = pv[j]; u1.s = pv[4 + j];
            acc += (float)u0.h * l0[j] + (float)u1.h * l1[j];
        }
    }
    acc += __shfl_xor(acc, 16);
    acc += __shfl_xor(acc, 32);
    if (lane < 16)
        atomicAdd(&wsum_g[b * 2048 + ktile * 16 + l15], acc);
}

// ---------------- k_out: out[b,d] = (1/S) sum_k w[b,k] * v[b,k,d] -----------
__global__ __launch_bounds__(256) void k_out(
    const float* __restrict__ wsum_g, const unsigned short* __restrict__ vb,
    float* __restrict__ outp)
{
    int b = blockIdx.y;
    int d = threadIdx.x;
    int k0 = blockIdx.x * 128;
    float acc = 0.f;
#pragma unroll 4
    for (int k = k0; k < k0 + 128; ++k) {
        float wv = wsum_g[b * 2048 + k];
        acc += wv * bf2f(vb[(b * 2048 + k) * 256 + d]);
    }
    atomicAdd(&outp[b * 256 + d], acc * (1.0f / 2048.0f));
}

extern "C" void kernel_launch(void* const* d_in, const int* in_sizes, int n_in,
                              void* d_out, int out_size, void* d_ws, size_t ws_size,
                              hipStream_t stream)
{
    const float* nodes = (const float*)d_in[0];
    const int*   mask  = (const int*)d_in[1];
    const float* Wq    = (const float*)d_in[2];
    const float* bq    = (const float*)d_in[3];
    const float* Wk    = (const float*)d_in[4];
    const float* bk    = (const float*)d_in[5];
    const float* Wv    = (const float*)d_in[6];
    const float* bv    = (const float*)d_in[7];
    float* out = (float*)d_out;

    // workspace layout (ushort units)
    unsigned short* qb  = (unsigned short*)d_ws;        // 16384*256
    unsigned short* kb  = qb + 4194304;
    unsigned short* vb  = kb + 4194304;
    float* lsum = (float*)(vb + 4194304);               // 16384
    float* wsum = lsum + 16384;                         // 16384
    unsigned short* pbuf = (unsigned short*)(wsum + 16384);  // 33554432

    hipMemsetAsync(lsum, 0, 16384 * sizeof(float), stream);
    hipMemsetAsync(wsum, 0, 16384 * sizeof(float), stream);
    hipMemsetAsync(d_out, 0, 2048 * sizeof(float), stream);

    k_proj3<<<dim3(128, 2, 3), 256, 0, stream>>>(nodes, Wq, Wk, Wv, bq, bk, bv,
                                                 qb, kb, vb);
    k_attn<<<dim3(16, 8, 8), 256, 0, stream>>>(qb, kb, mask, lsum, pbuf);
    k_wred3<<<dim3(2, 16, 8), 512, 0, stream>>>(pbuf, lsum, wsum);
    k_out<<<dim3(16, 8), 256, 0, stream>>>(wsum, vb, out);
}